// Round 1
// baseline (11386.426 us; speedup 1.0000x reference)
//
#include <hip/hip_runtime.h>
#include <math.h>

// ---- problem constants ----
#define NT   64      // timesteps
#define NB   16      // batch
#define INS  256     // input size
#define OUTS 256     // output size
#define WL   128     // word length
#define NC   256     // memory cells
#define NR   4       // read heads
#define HIDN 512     // lstm hidden
#define G4   2048    // 4*HIDN
#define WCH  391     // write channels
#define COUT 927     // controller output channels
#define EPSF 1e-6f

__device__ __forceinline__ float sigf(float x){ return 1.0f/(1.0f+expf(-x)); }
__device__ __forceinline__ float oneplusf(float x){ return fmaxf(x,0.0f)+log1pf(expf(-fabsf(x)))+1.0f; }

__device__ __forceinline__ float waveSum(float v){
#pragma unroll
  for(int o=32;o>0;o>>=1) v += __shfl_down(v,o,64);
  return v;
}
__device__ __forceinline__ float waveMax(float v){
#pragma unroll
  for(int o=32;o>0;o>>=1) v = fmaxf(v,__shfl_down(v,o,64));
  return v;
}
// 256-thread block reductions (deterministic fixed tree)
__device__ float blockSum(float v, float* red){
  int lane=threadIdx.x&63, wid=threadIdx.x>>6;
  v=waveSum(v);
  __syncthreads();
  if(lane==0) red[wid]=v;
  __syncthreads();
  return red[0]+red[1]+red[2]+red[3];
}
__device__ float blockMax(float v, float* red){
  int lane=threadIdx.x&63, wid=threadIdx.x>>6;
  v=waveMax(v);
  __syncthreads();
  if(lane==0) red[wid]=v;
  __syncthreads();
  return fmaxf(fmaxf(red[0],red[1]),fmaxf(red[2],red[3]));
}

__global__ void k_zero(float* p, int n){
  int i = blockIdx.x*blockDim.x + threadIdx.x;
  int s = gridDim.x*blockDim.x;
  for(; i<n; i+=s) p[i]=0.0f;
}

// ---- output head (shared by fused + final kernels) ----
__device__ __forceinline__ void out_head(const float* __restrict__ h, const float* __restrict__ rdata,
    const float* __restrict__ Wo, const float* __restrict__ bo,
    const float* __restrict__ Wr, const float* __restrict__ br,
    float* __restrict__ out_row, int ob){
  int bi = threadIdx.x & 15, jl = threadIdx.x >> 4;
  int j = ob*16 + jl;                       // ob in [0,16) -> j in [0,256)
  const float* hr = h + bi*HIDN;
  const float* rr = rdata + bi*HIDN;
  float acc = bo[j] + br[j];
  for(int k=0;k<HIDN;k++) acc += hr[k]*Wo[k*OUTS+j];
  for(int k=0;k<HIDN;k++) acc += rr[k]*Wr[k*OUTS+j];
  out_row[bi*OUTS+j] = acc;
}

// ---- gates GEMM (partials over 8 k-splits) + previous step's output head ----
// blocks 0..127: gates.  jb = blk>>3 (16 j-tiles of 128), kb = blk&7 (k range of 160)
// blocks 128..143: out(t-1)
__global__ __launch_bounds__(256) void k_gates_out(
    const float* __restrict__ in_data, const float* __restrict__ Wx, const float* __restrict__ Wh,
    const float* __restrict__ Wo, const float* __restrict__ bo,
    const float* __restrict__ Wr, const float* __restrict__ br,
    const float* __restrict__ h_prev, const float* __restrict__ rdata,
    float* __restrict__ gpart, float* __restrict__ out, int t)
{
  int blk = blockIdx.x;
  if (blk < 128){
    int jb = blk >> 3, kb = blk & 7;
    int jg = threadIdx.x & 15, bi = threadIdx.x >> 4;
    int j0 = jb*128 + jg*8;
    float acc[8];
#pragma unroll
    for(int i=0;i<8;i++) acc[i]=0.0f;
    int klo = kb*160, khi = klo+160;

    // segment 0: x_t (k in [0,256)), weight rows Wx[k]
    {
      int lo = klo, hi = khi<256?khi:256;
      const float* xrow = in_data + (size_t)t*NB*INS + bi*INS;
      for(int k=lo;k<hi;k++){
        float a = xrow[k];
        const float* wr_ = Wx + (size_t)k*G4 + j0;
        float4 w0 = *(const float4*)wr_;
        float4 w1 = *(const float4*)(wr_+4);
        acc[0]+=a*w0.x; acc[1]+=a*w0.y; acc[2]+=a*w0.z; acc[3]+=a*w0.w;
        acc[4]+=a*w1.x; acc[5]+=a*w1.y; acc[6]+=a*w1.z; acc[7]+=a*w1.w;
      }
    }
    // segment 1: prev_rdata (k in [256,768)), weight rows Wx[k]
    {
      int lo = klo>256?klo:256, hi = khi<768?khi:768;
      const float* rrow = rdata + bi*(NR*WL);
      for(int k=lo;k<hi;k++){
        float a = rrow[k-256];
        const float* wr_ = Wx + (size_t)k*G4 + j0;
        float4 w0 = *(const float4*)wr_;
        float4 w1 = *(const float4*)(wr_+4);
        acc[0]+=a*w0.x; acc[1]+=a*w0.y; acc[2]+=a*w0.z; acc[3]+=a*w0.w;
        acc[4]+=a*w1.x; acc[5]+=a*w1.y; acc[6]+=a*w1.z; acc[7]+=a*w1.w;
      }
    }
    // segment 2: h_prev (k in [768,1280)), weight rows Wh[k-768]
    {
      int lo = klo>768?klo:768, hi = khi;
      const float* hrow = h_prev + bi*HIDN;
      for(int k=lo;k<hi;k++){
        float a = hrow[k-768];
        const float* wr_ = Wh + (size_t)(k-768)*G4 + j0;
        float4 w0 = *(const float4*)wr_;
        float4 w1 = *(const float4*)(wr_+4);
        acc[0]+=a*w0.x; acc[1]+=a*w0.y; acc[2]+=a*w0.z; acc[3]+=a*w0.w;
        acc[4]+=a*w1.x; acc[5]+=a*w1.y; acc[6]+=a*w1.z; acc[7]+=a*w1.w;
      }
    }
    float* gp = gpart + ((size_t)(kb*NB+bi))*G4 + j0;
#pragma unroll
    for(int i=0;i<8;i++) gp[i]=acc[i];
  } else {
    if (t==0) return;
    out_head(h_prev, rdata, Wo, bo, Wr, br, out + (size_t)(t-1)*NB*OUTS, blk-128);
  }
}

// ---- LSTM cell: reduce gate partials, update c,h ----
__global__ __launch_bounds__(256) void k_lstm(
    const float* __restrict__ gpart, const float* __restrict__ b_lstm,
    const float* __restrict__ c_in, float* __restrict__ c_out, float* __restrict__ h_out)
{
  int idx = blockIdx.x*256 + threadIdx.x;   // [0, NB*HIDN)
  int bi = idx >> 9, jj = idx & 511;
  float g[4];
#pragma unroll
  for(int s=0;s<4;s++){
    int col = s*HIDN + jj;
    float acc = b_lstm[col];
    for(int kb=0;kb<8;kb++) acc += gpart[((size_t)(kb*NB+bi))*G4 + col];
    g[s]=acc;
  }
  float c = sigf(g[1])*c_in[idx] + sigf(g[0])*tanhf(g[2]);
  float h = sigf(g[3])*tanhf(c);
  c_out[idx]=c; h_out[idx]=h;
}

// ---- controls head: controls = clip(h @ Wc + bc) ----
// grid 58 blocks; 256 threads = 16 j x 16 bi
__global__ __launch_bounds__(256) void k_ctrl(
    const float* __restrict__ h, const float* __restrict__ Wc, const float* __restrict__ bc,
    float* __restrict__ controls)
{
  __shared__ float s_h[HIDN*17];            // [k][bi] padded to 17 for bank-conflict-free
  for(int i=threadIdx.x; i<NB*HIDN; i+=256){
    int bi = i>>9, k = i&511;
    s_h[k*17+bi] = h[i];                    // coalesced global read
  }
  __syncthreads();
  int bi = threadIdx.x & 15, jl = threadIdx.x >> 4;
  int j = blockIdx.x*16 + jl;
  if (j < COUT){
    float acc = bc[j];
    for(int k=0;k<HIDN;k++) acc += s_h[k*17+bi]*Wc[(size_t)k*COUT + j];
    controls[bi*COUT+j] = fminf(fmaxf(acc,-20.0f),20.0f);
  }
}

// ---- the per-batch memory/addressing/read step ----
// grid = 16 (one block per batch), 256 threads (thread = cell index n)
__global__ __launch_bounds__(256) void k_step(
    const float* __restrict__ controls_g,
    float* __restrict__ mem, float* __restrict__ usages, float* __restrict__ link,
    float* __restrict__ prec, float* __restrict__ w_dist, float* __restrict__ r_dist,
    float* __restrict__ rdata)
{
  int b = blockIdx.x, n = threadIdx.x;
  __shared__ float s_ctrl[COUT];
  __shared__ float s_prd[NR][NC];
  __shared__ float s_u[NC], s_su[NC], s_shift[NC];
  __shared__ float s_wd[NC], s_psi[NC], s_pre[NC], s_mn[NC];
  __shared__ float s_fwd[NR][NC], s_bwd[NR][NC];
  __shared__ float s_key[WL], s_er[WL];
  __shared__ float s_red[4];
  __shared__ float s_tmp[NC];

  const float* cb = controls_g + b*COUT;
  for(int i=n;i<COUT;i+=256) s_ctrl[i]=cb[i];
#pragma unroll
  for(int r=0;r<NR;r++) s_prd[r][n] = r_dist[((size_t)b*NR+r)*NC + n];
  s_pre[n] = prec[b*NC+n];
  __syncthreads();

  // scalars
  float fr[NR];
#pragma unroll
  for(int r=0;r<NR;r++) fr[r] = sigf(s_ctrl[3*WL+r]);
  float w_beta = oneplusf(s_ctrl[3*WL+NR]);
  float a_gate = sigf(s_ctrl[3*WL+NR+1]);
  float w_gate = sigf(s_ctrl[3*WL+NR+2]);

  // psi, usage update
  float psi = 1.0f;
#pragma unroll
  for(int r=0;r<NR;r++) psi *= 1.0f - fr[r]*s_prd[r][n];
  s_psi[n]=psi;
  float pw = w_dist[b*NC+n];
  float u  = usages[b*NC+n];
  u = (u + pw - u*pw)*psi;
  usages[b*NC+n]=u;
  float u2 = u*(1.0f-EPSF)+EPSF;
  s_u[n]=u2;
  if (n < WL) s_er[n] = sigf(s_ctrl[WL+n]);   // erase vector (precompute)
  __syncthreads();

  // allocation: stable rank (matches stable argsort), serial cumprod
  int rk=0;
  for(int j=0;j<NC;j++){
    float uj=s_u[j];
    rk += (uj<u2) || (uj==u2 && j<n);
  }
  s_su[rk]=u2;
  __syncthreads();
  if(n==0){
    float run=1.0f;
    for(int i=0;i<NC;i++){ s_shift[i]=run; run*=s_su[i]; }
  }
  __syncthreads();
  float alloc = (1.0f - s_su[rk])*s_shift[rk];

  // write-key cosine addressing on OLD memory
  if(n<WL) s_key[n]=s_ctrl[n];
  __syncthreads();
  float kn2 = blockSum((n<WL)? s_key[n]*s_key[n] : 0.0f, s_red);
  float kn = sqrtf(kn2);
  size_t mbase = (size_t)b*NC*WL;
  const float4* mrow = (const float4*)(mem + mbase + (size_t)n*WL);
  float dt=0.0f, mn2=0.0f;
#pragma unroll 4
  for(int w4=0;w4<WL/4;w4++){
    float4 m4 = mrow[w4];
    dt  += m4.x*s_key[4*w4] + m4.y*s_key[4*w4+1] + m4.z*s_key[4*w4+2] + m4.w*s_key[4*w4+3];
    mn2 += m4.x*m4.x + m4.y*m4.y + m4.z*m4.z + m4.w*m4.w;
  }
  float logit = dt/(kn*sqrtf(mn2)+EPSF)*w_beta;
  float mx = blockMax(logit, s_red);
  float ee = expf(logit-mx);
  float se = blockSum(ee, s_red);
  float cw = ee/se;

  // write distribution, precedence
  float wd = w_gate*(a_gate*alloc + (1.0f-a_gate)*cw);
  s_wd[n]=wd;
  w_dist[b*NC+n]=wd;
  __syncthreads();
  float swd = blockSum(wd, s_red);
  prec[b*NC+n] = (1.0f-swd)*s_pre[n] + wd;   // link below uses s_pre (LDS copy)

  // memory update (coalesced over flat n*WL+w)
  for(int i=0;i<(NC*WL)/256;i++){
    int flat = i*256 + n;
    int nn = flat >> 7, ww = flat & (WL-1);
    float m = mem[mbase+flat];
    m = m*s_psi[nn]*(1.0f - s_wd[nn]*s_er[ww]) + s_wd[nn]*s_ctrl[2*WL+ww];
    mem[mbase+flat]=m;
  }

  // link update (thread = column n), bwd fused (column-local accumulation)
  float bw[NR]={0,0,0,0};
  float wdn = s_wd[n], pren = s_pre[n];
  size_t lbase = (size_t)b*NC*NC;
  for(int i=0;i<NC;i++){
    float l = link[lbase + (size_t)i*NC + n];
    float wi = s_wd[i];
    float lnew = (i==n) ? 0.0f : ((1.0f-wi-wdn)*l + wi*pren);
    link[lbase + (size_t)i*NC + n] = lnew;
#pragma unroll
    for(int r=0;r<NR;r++) bw[r] += lnew * s_prd[r][i];
  }
#pragma unroll
  for(int r=0;r<NR;r++) s_bwd[r][n]=bw[r];
  __syncthreads();   // link fully written + mem fully written

  // fwd = link_new @ prd (row read per thread, L2-warm)
  {
    float fw[NR]={0,0,0,0};
    const float4* lrow = (const float4*)(link + lbase + (size_t)n*NC);
    for(int j4=0;j4<NC/4;j4++){
      float4 l4 = lrow[j4];
      int j=4*j4;
#pragma unroll
      for(int r=0;r<NR;r++)
        fw[r] += l4.x*s_prd[r][j] + l4.y*s_prd[r][j+1] + l4.z*s_prd[r][j+2] + l4.w*s_prd[r][j+3];
    }
#pragma unroll
    for(int r=0;r<NR;r++) s_fwd[r][n]=fw[r];
  }
  __syncthreads();

  // sharpen fwd/bwd
#pragma unroll
  for(int r=0;r<NR;r++){
    float ff = oneplusf(s_ctrl[919+r]);
    float d = s_fwd[r][n]+EPSF;
    float m1 = blockMax(d, s_red);
    d = powf(d/m1, ff);
    float s1 = blockSum(d, s_red);
    s_fwd[r][n] = d/s1;

    float fb = oneplusf(s_ctrl[919+NR+r]);
    float d2 = s_bwd[r][n]+EPSF;
    float m2 = blockMax(d2, s_red);
    d2 = powf(d2/m2, fb);
    float s2 = blockSum(d2, s_red);
    s_bwd[r][n] = d2/s2;
  }

  // new memory norms
  {
    const float4* mr2 = (const float4*)(mem + mbase + (size_t)n*WL);
    float a=0.0f;
#pragma unroll 4
    for(int w4=0;w4<WL/4;w4++){
      float4 m4 = mr2[w4];
      a += m4.x*m4.x + m4.y*m4.y + m4.z*m4.z + m4.w*m4.w;
    }
    s_mn[n]=sqrtf(a);
  }
  __syncthreads();

  // read addressing per head
  for(int r=0;r<NR;r++){
    int rb_off = WCH + r*(WL+4);
    if(n<WL) s_key[n] = s_ctrl[rb_off + n];
    __syncthreads();
    float rbeta = oneplusf(s_ctrl[rb_off + WL]);
    float kn2r = blockSum((n<WL)? s_key[n]*s_key[n] : 0.0f, s_red);
    float knr = sqrtf(kn2r);
    const float4* mr3 = (const float4*)(mem + mbase + (size_t)n*WL);
    float dtr=0.0f;
#pragma unroll 4
    for(int w4=0;w4<WL/4;w4++){
      float4 m4 = mr3[w4];
      dtr += m4.x*s_key[4*w4] + m4.y*s_key[4*w4+1] + m4.z*s_key[4*w4+2] + m4.w*s_key[4*w4+3];
    }
    float lg = dtr/(knr*s_mn[n]+EPSF)*rbeta;
    float mxr = blockMax(lg, s_red);
    float er_ = expf(lg-mxr);
    float ser = blockSum(er_, s_red);
    float cr = er_/ser;
    // modes softmax (3)
    float m0=s_ctrl[rb_off+WL+1], m1m=s_ctrl[rb_off+WL+2], m2m=s_ctrl[rb_off+WL+3];
    float mm = fmaxf(m0,fmaxf(m1m,m2m));
    float e0=expf(m0-mm), e1=expf(m1m-mm), e2=expf(m2m-mm);
    float es=e0+e1+e2;
    float rdv = (e0*s_bwd[r][n] + e1*cr + e2*s_fwd[r][n])/es;
    __syncthreads();                 // all reads of s_key done before next head overwrites
    s_prd[r][n]=rdv;                 // reuse prd slot for new r_dist
    r_dist[((size_t)b*NR+r)*NC + n] = rdv;
  }
  __syncthreads();

  // r_data[r][w] = sum_n r_dist[r][n] * mem[n][w]   (split n in halves across threads)
  {
    int w = n & (WL-1), half = n >> 7;
    for(int r=0;r<NR;r++){
      float acc=0.0f;
      for(int i=0;i<NC/2;i++){
        int nn = half*(NC/2)+i;
        acc += s_prd[r][nn]*mem[mbase + (size_t)nn*WL + w];
      }
      s_tmp[n]=acc;
      __syncthreads();
      if(n<WL) rdata[((size_t)b*NR+r)*WL + n] = s_tmp[n]+s_tmp[n+WL];
      __syncthreads();
    }
  }
}

// final output head for t = NT-1
__global__ __launch_bounds__(256) void k_out(
    const float* __restrict__ h, const float* __restrict__ rdata,
    const float* __restrict__ Wo, const float* __restrict__ bo,
    const float* __restrict__ Wr, const float* __restrict__ br,
    float* __restrict__ out)
{
  out_head(h, rdata, Wo, bo, Wr, br, out + (size_t)(NT-1)*NB*OUTS, blockIdx.x);
}

extern "C" void kernel_launch(void* const* d_in, const int* in_sizes, int n_in,
                              void* d_out, int out_size, void* d_ws, size_t ws_size,
                              hipStream_t stream) {
  const float* in_data = (const float*)d_in[0];
  const float* Wx      = (const float*)d_in[1];
  const float* Wh      = (const float*)d_in[2];
  const float* b_lstm  = (const float*)d_in[3];
  const float* Wc      = (const float*)d_in[4];
  const float* bc      = (const float*)d_in[5];
  const float* Wo      = (const float*)d_in[6];
  const float* bo      = (const float*)d_in[7];
  const float* Wr      = (const float*)d_in[8];
  const float* br      = (const float*)d_in[9];
  float* out = (float*)d_out;
  float* ws  = (float*)d_ws;

  // workspace layout (floats)
  size_t off = 0;
  float* mem_    = ws + off; off += (size_t)NB*NC*WL;      // 524288
  float* link_   = ws + off; off += (size_t)NB*NC*NC;      // 1048576
  float* usages_ = ws + off; off += NB*NC;
  float* prec_   = ws + off; off += NB*NC;
  float* wdist_  = ws + off; off += NB*NC;
  float* rdist_  = ws + off; off += NB*NR*NC;
  float* rdata_  = ws + off; off += NB*NR*WL;
  float* h0_     = ws + off; off += NB*HIDN;
  float* h1_     = ws + off; off += NB*HIDN;
  float* c0_     = ws + off; off += NB*HIDN;
  float* c1_     = ws + off; off += NB*HIDN;
  size_t state_floats = off;
  float* gpart_  = ws + off; off += (size_t)8*NB*G4;       // 262144
  float* ctrl_   = ws + off; off += NB*COUT;

  // zero carry state (required every call: harness does not re-poison)
  k_zero<<<256,256,0,stream>>>(ws, (int)state_floats);

  for(int t=0;t<NT;t++){
    float* h_in  = (t&1) ? h1_ : h0_;
    float* h_out = (t&1) ? h0_ : h1_;
    float* c_in  = (t&1) ? c1_ : c0_;
    float* c_out = (t&1) ? c0_ : c1_;
    k_gates_out<<<144,256,0,stream>>>(in_data,Wx,Wh,Wo,bo,Wr,br,h_in,rdata_,gpart_,out,t);
    k_lstm<<<32,256,0,stream>>>(gpart_,b_lstm,c_in,c_out,h_out);
    k_ctrl<<<58,256,0,stream>>>(h_out,Wc,bc,ctrl_);
    k_step<<<16,256,0,stream>>>(ctrl_,mem_,usages_,link_,prec_,wdist_,rdist_,rdata_);
  }
  // t=63 output head: h(63) is in h0_ (t=63 odd -> h_out = h0_), rdata_ holds rdata(63)
  k_out<<<16,256,0,stream>>>(h0_, rdata_, Wo,bo,Wr,br, out);
}

// Round 2
// 8546.024 us; speedup vs baseline: 1.3324x; 1.3324x over previous
//
#include <hip/hip_runtime.h>
#include <math.h>

#define NT   64
#define NB   16
#define INS  256
#define OUTS 256
#define WL   128
#define NC   256
#define NR   4
#define HIDN 512
#define G4   2048
#define WCH  391
#define COUT 927
#define EPSF 1e-6f
#define FT   1024     // fused kernel block size
#define NBLK 16       // fused kernel grid size (one per batch; all co-resident)

__device__ __forceinline__ float sigf(float x){ return 1.0f/(1.0f+expf(-x)); }
__device__ __forceinline__ float oneplusf(float x){ return fmaxf(x,0.0f)+log1pf(expf(-fabsf(x)))+1.0f; }

__device__ __forceinline__ float waveSum(float v){
#pragma unroll
  for(int o=32;o>0;o>>=1) v += __shfl_down(v,o,64);
  return v;
}
__device__ __forceinline__ float waveMax(float v){
#pragma unroll
  for(int o=32;o>0;o>>=1) v = fmaxf(v,__shfl_down(v,o,64));
  return v;
}

// reduce over v[0..255] (row 0 only), all 1024 threads participate; each value
// counted 4x for sum -> *0.25f (exact). Returns broadcast value.
__device__ float redAll(const float* v, bool isMax, float* s_red){
  int n = threadIdx.x & 255;
  __syncthreads();                 // v ready
  float x = v[n];
  x = isMax ? waveMax(x) : waveSum(x);
  if ((threadIdx.x & 63)==0) s_red[threadIdx.x>>6] = x;
  __syncthreads();
  float r = s_red[0];
  if (isMax){ for(int i=1;i<16;i++) r = fmaxf(r, s_red[i]); }
  else      { for(int i=1;i<16;i++) r += s_red[i]; r *= 0.25f; }
  __syncthreads();                 // allow s_red reuse
  return r;
}

// reduce each of 4 rows v[q][0..255] -> s_scal[q]; thread (n,q) handles row q.
__device__ void red4(const float* v, bool isMax, float* s_red, float* s_scal){
  int n = threadIdx.x & 255, q = threadIdx.x >> 8;
  __syncthreads();                 // v ready
  float x = v[q*NC + n];
  x = isMax ? waveMax(x) : waveSum(x);
  if ((threadIdx.x & 63)==0) s_red[threadIdx.x>>6] = x;   // wid = q*4 + (n>>6)
  __syncthreads();
  if (threadIdx.x < 4){
    const float* p = s_red + threadIdx.x*4;
    s_scal[threadIdx.x] = isMax ? fmaxf(fmaxf(p[0],p[1]),fmaxf(p[2],p[3]))
                                : (p[0]+p[1]+p[2]+p[3]);
  }
  __syncthreads();
}

// device-scope soft grid barrier: NBLK co-resident blocks, monotone target.
__device__ __forceinline__ void gridbar(int* bar, int target){
  __syncthreads();
  if (threadIdx.x == 0){
    __threadfence();
    __hip_atomic_fetch_add(bar, 1, __ATOMIC_ACQ_REL, __HIP_MEMORY_SCOPE_AGENT);
    while (__hip_atomic_load(bar, __ATOMIC_ACQUIRE, __HIP_MEMORY_SCOPE_AGENT) < target){
      __builtin_amdgcn_s_sleep(2);
    }
    __threadfence();
  }
  __syncthreads();
}

__global__ void k_zero(float* p, int n){
  int i = blockIdx.x*blockDim.x + threadIdx.x;
  int s = gridDim.x*blockDim.x;
  for(; i<n; i+=s) p[i]=0.0f;
}

// ---- xpart[t*NB+bi][2048] = x_t @ Wx[0:256]  (once, fully parallel) ----
__global__ __launch_bounds__(256) void k_xpart(
    const float* __restrict__ in_data, const float* __restrict__ Wx, float* __restrict__ xpart)
{
  int jb = blockIdx.x & 15, rt = blockIdx.x >> 4;     // 16 j-tiles x 64 row-tiles
  int jg = threadIdx.x & 15, rl = threadIdx.x >> 4;
  int row = rt*16 + rl;
  int j0 = jb*128 + jg*8;
  const float* x = in_data + (size_t)row*INS;
  float acc[8];
#pragma unroll
  for(int i=0;i<8;i++) acc[i]=0.0f;
  for(int k=0;k<INS;k++){
    float a = x[k];
    const float* w = Wx + (size_t)k*G4 + j0;
    float4 w0 = *(const float4*)w, w1 = *(const float4*)(w+4);
    acc[0]+=a*w0.x; acc[1]+=a*w0.y; acc[2]+=a*w0.z; acc[3]+=a*w0.w;
    acc[4]+=a*w1.x; acc[5]+=a*w1.y; acc[6]+=a*w1.z; acc[7]+=a*w1.w;
  }
  float* xp = xpart + (size_t)row*G4 + j0;
#pragma unroll
  for(int i=0;i<8;i++) xp[i]=acc[i];
}

// ---- recurrent gates GEMM partials + output-head partials for t-1 ----
// blocks 0..255: gates, jb = blk>>4 (16 j-tiles of 128), kb = blk&15 (K-range 64)
//   kb<8  -> rdata part (Wx rows 256+k), kb>=8 -> h part (Wh rows k-512)
// blocks 256..319: out-head partials: kq = (blk-256)>>4, jb = (blk-256)&15
__global__ __launch_bounds__(256) void k_gates(
    const float* __restrict__ Wx, const float* __restrict__ Wh,
    const float* __restrict__ Wo, const float* __restrict__ Wr,
    const float* __restrict__ h_prev, const float* __restrict__ rdata,
    float* __restrict__ gpart, float* __restrict__ opart, int t)
{
  int blk = blockIdx.x;
  if (blk < 256){
    if (t >= NT) return;
    int jb = blk >> 4, kb = blk & 15;
    int jg = threadIdx.x & 15, bi = threadIdx.x >> 4;
    int j0 = jb*128 + jg*8;
    int klo = kb*64;
    const float* act; const float* wb;
    if (kb < 8){ act = rdata + bi*(NR*WL) + klo;      wb = Wx + (size_t)(INS+klo)*G4 + j0; }
    else       { act = h_prev + bi*HIDN + (klo-512);  wb = Wh + (size_t)(klo-512)*G4 + j0; }
    float acc[8];
#pragma unroll
    for(int i=0;i<8;i++) acc[i]=0.0f;
    for(int kk=0;kk<64;kk++){
      float a = act[kk];
      const float* w = wb + (size_t)kk*G4;
      float4 w0 = *(const float4*)w, w1 = *(const float4*)(w+4);
      acc[0]+=a*w0.x; acc[1]+=a*w0.y; acc[2]+=a*w0.z; acc[3]+=a*w0.w;
      acc[4]+=a*w1.x; acc[5]+=a*w1.y; acc[6]+=a*w1.z; acc[7]+=a*w1.w;
    }
    float* gp = gpart + ((size_t)(kb*NB+bi))*G4 + j0;
#pragma unroll
    for(int i=0;i<8;i++) gp[i]=acc[i];
  } else {
    if (t == 0) return;
    int ob = blk - 256;
    int kq = ob >> 4, jb = ob & 15;
    int jl = threadIdx.x & 15, bi = threadIdx.x >> 4;
    int j = jb*16 + jl;
    const float* act; const float* W;
    if (kq < 2){ act = rdata + bi*(NR*WL) + kq*256;     W = Wr + (size_t)(kq*256)*OUTS; }
    else       { act = h_prev + bi*HIDN + (kq-2)*256;   W = Wo + (size_t)((kq-2)*256)*OUTS; }
    float acc = 0.0f;
    for(int kk=0;kk<256;kk++) acc += act[kk]*W[(size_t)kk*OUTS + j];
    opart[((size_t)(kq*NB+bi))*OUTS + j] = acc;
  }
}

// final out(NT-1) reduce
__global__ __launch_bounds__(256) void k_ored(
    const float* __restrict__ opart, const float* __restrict__ bo, const float* __restrict__ br,
    float* __restrict__ out)
{
  int e = blockIdx.x*256 + threadIdx.x;   // 4096
  int bi = e >> 8, j = e & 255;
  float acc = bo[j] + br[j];
#pragma unroll
  for(int kq=0;kq<4;kq++) acc += opart[((size_t)(kq*NB+bi))*OUTS + j];
  out[(size_t)(NT-1)*NB*OUTS + e] = acc;
}

// ---- fused per-step kernel: phase1 LSTM (+out(t-1) reduce) | bar | phase2 ctrl | bar | phase3 step ----
__global__ __launch_bounds__(1024) void k_fused(
    const float* __restrict__ xpart, const float* __restrict__ gpart, const float* __restrict__ b_lstm,
    const float* __restrict__ opart, const float* __restrict__ bo, const float* __restrict__ br,
    const float* __restrict__ Wc, const float* __restrict__ bc,
    const float* __restrict__ c_in, float* __restrict__ c_out, float* __restrict__ h_out,
    float* __restrict__ ctrl, float* __restrict__ out,
    float* __restrict__ mem, float* __restrict__ usages, float* __restrict__ link,
    float* __restrict__ prec, float* __restrict__ w_dist, float* __restrict__ r_dist,
    float* __restrict__ rdata, int* bar, int t)
{
  int tid = threadIdx.x, blk = blockIdx.x;
  __shared__ float SH[13104];
  __shared__ float s_red[16];
  __shared__ float s_scal[4];

  // ---------- phase 1: LSTM cell + out(t-1) reduce ----------
  {
    int item = blk*FT + tid;
    if (item < NB*HIDN){
      int bi = item >> 9, jj = item & 511;
      float g[4];
#pragma unroll
      for(int s=0;s<4;s++){
        int col = s*HIDN + jj;
        float acc = b_lstm[col] + xpart[((size_t)t*NB + bi)*G4 + col];
#pragma unroll
        for(int kb=0;kb<16;kb++) acc += gpart[((size_t)(kb*NB+bi))*G4 + col];
        g[s]=acc;
      }
      float c = sigf(g[1])*c_in[item] + sigf(g[0])*tanhf(g[2]);
      float h = sigf(g[3])*tanhf(c);
      c_out[item]=c; h_out[item]=h;
    } else if (t > 0 && item < NB*HIDN + NB*OUTS){
      int e = item - NB*HIDN;
      int bi = e >> 8, j = e & 255;
      float acc = bo[j] + br[j];
#pragma unroll
      for(int kq=0;kq<4;kq++) acc += opart[((size_t)(kq*NB+bi))*OUTS + j];
      out[((size_t)(t-1)*NB + bi)*OUTS + j] = acc;
    }
  }
  gridbar(bar, NBLK*(2*t+1));

  // ---------- phase 2: controls = clip(h @ Wc + bc) ----------
  if (blk < 15){
    float* s_h = SH;                       // [512][17]
    for(int i=tid; i<NB*HIDN; i+=FT){
      int bi = i>>9, k = i&511;
      s_h[k*17+bi] = h_out[i];
    }
    __syncthreads();
    int jl = tid & 63, bi = tid >> 6;
    int j = blk*64 + jl;
    if (j < COUT){
      float acc = bc[j];
      const float* wc = Wc + j;
#pragma unroll 8
      for(int k=0;k<HIDN;k++) acc += s_h[k*17+bi]*wc[(size_t)k*COUT];
      ctrl[bi*COUT + j] = fminf(fmaxf(acc,-20.0f),20.0f);
    }
  }
  gridbar(bar, NBLK*(2*t+2));

  // ---------- phase 3: per-batch memory step ----------
  int b = blk;
  int n = tid & 255, q = tid >> 8;
  float* s_ctrl = SH;            // 928
  float* s_prd  = SH+928;        // [4][256]
  float* s_u    = SH+1952;
  float* s_su   = SH+2208;
  float* s_shift= SH+2464;
  float* s_wd   = SH+2720;
  float* s_psi  = SH+2976;
  float* s_pre  = SH+3232;
  float* s_mn   = SH+3488;
  float* s_fwd  = SH+3744;       // [4][256]
  float* s_bwd  = SH+4768;       // [4][256]
  float* s_er   = SH+5792;       // 128
  float* s_rkey = SH+5920;       // [4][128]
  float* s_qa   = SH+6432;       // [4][256] scratch
  float* s_qb   = SH+7456;       // [4][256] scratch
  float* s_p16  = SH+8480;       // [4][4][256] scratch

  {
    const float* cb = ctrl + b*COUT;
    for(int i=tid;i<COUT;i+=FT) s_ctrl[i]=cb[i];
    s_prd[q*NC+n] = r_dist[((size_t)b*NR+q)*NC + n];
    if (tid < NC) s_pre[tid] = prec[b*NC+tid];
  }
  __syncthreads();

  float w_beta = oneplusf(s_ctrl[3*WL+NR]);
  float a_gate = sigf(s_ctrl[3*WL+NR+1]);
  float w_gate = sigf(s_ctrl[3*WL+NR+2]);

  if (q==0){
    float psi = 1.0f;
#pragma unroll
    for(int r=0;r<NR;r++) psi *= 1.0f - sigf(s_ctrl[3*WL+r])*s_prd[r*NC+n];
    s_psi[n]=psi;
    float pw = w_dist[b*NC+n];
    float u  = usages[b*NC+n];
    u = (u + pw - u*pw)*psi;
    usages[b*NC+n]=u;
    s_u[n] = u*(1.0f-EPSF)+EPSF;
  }
  if (tid < WL) s_er[tid] = sigf(s_ctrl[WL+tid]);
  __syncthreads();

  // allocation: stable rank (q-split partial counts)
  {
    float u2 = s_u[n];
    int cnt=0;
#pragma unroll 8
    for(int jj=0;jj<64;jj++){
      int j = q*64+jj;
      float uj = s_u[j];
      cnt += (uj<u2) || (uj==u2 && j<n);
    }
    s_qa[q*NC+n] = (float)cnt;
  }
  __syncthreads();
  int rk = 0;
  if (q==0){
    rk = (int)(s_qa[n]+s_qa[NC+n]+s_qa[2*NC+n]+s_qa[3*NC+n]);
    s_su[rk] = s_u[n];
  }
  __syncthreads();
  if (tid==0){
    float run=1.0f;
    for(int i=0;i<NC;i++){ s_shift[i]=run; run*=s_su[i]; }
  }
  __syncthreads();
  float allocv = 0.0f;
  if (q==0) allocv = (1.0f - s_su[rk])*s_shift[rk];

  // write-content addressing on OLD memory (w-range split by q)
  float kn2 = 0.0f;
  for(int w=0;w<WL;w++) kn2 += s_ctrl[w]*s_ctrl[w];
  float kn = sqrtf(kn2);
  size_t mbase = (size_t)b*NC*WL;
  {
    const float4* mrow = (const float4*)(mem + mbase + (size_t)n*WL + q*32);
    float dt=0.0f, mn2=0.0f;
#pragma unroll
    for(int w4=0;w4<8;w4++){
      float4 m4 = mrow[w4];
      int w = q*32 + 4*w4;
      dt  += m4.x*s_ctrl[w] + m4.y*s_ctrl[w+1] + m4.z*s_ctrl[w+2] + m4.w*s_ctrl[w+3];
      mn2 += m4.x*m4.x + m4.y*m4.y + m4.z*m4.z + m4.w*m4.w;
    }
    s_qa[q*NC+n]=dt; s_p16[q*NC+n]=mn2;
  }
  __syncthreads();
  if (q==0){
    float dt  = s_qa[n]+s_qa[NC+n]+s_qa[2*NC+n]+s_qa[3*NC+n];
    float mn2 = s_p16[n]+s_p16[NC+n]+s_p16[2*NC+n]+s_p16[3*NC+n];
    s_qa[n] = dt/(kn*sqrtf(mn2)+EPSF)*w_beta;
  }
  float wmax = redAll(s_qa, true, s_red);
  if (q==0) s_qb[n] = expf(s_qa[n]-wmax);
  float wse = redAll(s_qb, false, s_red);
  if (q==0){
    float cw = s_qb[n]/wse;
    float wd = w_gate*(a_gate*allocv + (1.0f-a_gate)*cw);
    s_wd[n]=wd; w_dist[b*NC+n]=wd;
    s_qa[n]=wd;
  }
  float swd = redAll(s_qa, false, s_red);
  if (q==0) prec[b*NC+n] = (1.0f-swd)*s_pre[n] + s_wd[n];

  // memory update (flat, coalesced)
  for(int i=0;i<(NC*WL)/FT;i++){
    int flat = i*FT + tid;
    int nn = flat >> 7, ww = flat & (WL-1);
    float m = mem[mbase+flat];
    m = m*s_psi[nn]*(1.0f - s_wd[nn]*s_er[ww]) + s_wd[nn]*s_ctrl[2*WL+ww];
    mem[mbase+flat]=m;
  }

  // link update (column n, i-range split by q) + bwd partials
  {
    float bw0=0,bw1=0,bw2=0,bw3=0;
    float wdn = s_wd[n], pren = s_pre[n];
    size_t lb = (size_t)b*NC*NC;
    for(int ii=0;ii<64;ii++){
      int i = q*64+ii;
      size_t idx = lb + (size_t)i*NC + n;
      float l = link[idx];
      float wi = s_wd[i];
      float lnew = (i==n) ? 0.0f : ((1.0f-wi-wdn)*l + wi*pren);
      link[idx]=lnew;
      bw0 += lnew*s_prd[0*NC+i];
      bw1 += lnew*s_prd[1*NC+i];
      bw2 += lnew*s_prd[2*NC+i];
      bw3 += lnew*s_prd[3*NC+i];
    }
    s_p16[(q*4+0)*NC+n]=bw0; s_p16[(q*4+1)*NC+n]=bw1;
    s_p16[(q*4+2)*NC+n]=bw2; s_p16[(q*4+3)*NC+n]=bw3;
  }
  __syncthreads();
  s_bwd[q*NC+n] = s_p16[(0*4+q)*NC+n] + s_p16[(1*4+q)*NC+n] + s_p16[(2*4+q)*NC+n] + s_p16[(3*4+q)*NC+n];
  __syncthreads();

  // fwd = link_new row n (j-range split by q)
  {
    float fw0=0,fw1=0,fw2=0,fw3=0;
    size_t lb = (size_t)b*NC*NC;
    const float4* lrow = (const float4*)(link + lb + (size_t)n*NC + q*64);
#pragma unroll 4
    for(int j4=0;j4<16;j4++){
      float4 l4 = lrow[j4];
      int j = q*64 + 4*j4;
      fw0 += l4.x*s_prd[0*NC+j] + l4.y*s_prd[0*NC+j+1] + l4.z*s_prd[0*NC+j+2] + l4.w*s_prd[0*NC+j+3];
      fw1 += l4.x*s_prd[1*NC+j] + l4.y*s_prd[1*NC+j+1] + l4.z*s_prd[1*NC+j+2] + l4.w*s_prd[1*NC+j+3];
      fw2 += l4.x*s_prd[2*NC+j] + l4.y*s_prd[2*NC+j+1] + l4.z*s_prd[2*NC+j+2] + l4.w*s_prd[2*NC+j+3];
      fw3 += l4.x*s_prd[3*NC+j] + l4.y*s_prd[3*NC+j+1] + l4.z*s_prd[3*NC+j+2] + l4.w*s_prd[3*NC+j+3];
    }
    s_p16[(q*4+0)*NC+n]=fw0; s_p16[(q*4+1)*NC+n]=fw1;
    s_p16[(q*4+2)*NC+n]=fw2; s_p16[(q*4+3)*NC+n]=fw3;
  }
  __syncthreads();
  s_fwd[q*NC+n] = s_p16[(0*4+q)*NC+n] + s_p16[(1*4+q)*NC+n] + s_p16[(2*4+q)*NC+n] + s_p16[(3*4+q)*NC+n];

  // sharpen fwd (head = q, all 4 concurrent)
  s_qa[q*NC+n] = s_fwd[q*NC+n] + EPSF;
  red4(s_qa, true, s_red, s_scal);
  {
    float ff = oneplusf(s_ctrl[919+q]);
    float d = powf(s_qa[q*NC+n]/s_scal[q], ff);
    s_qa[q*NC+n] = d;
    red4(s_qa, false, s_red, s_scal);
    s_fwd[q*NC+n] = d/s_scal[q];
  }
  // sharpen bwd
  s_qb[q*NC+n] = s_bwd[q*NC+n] + EPSF;
  red4(s_qb, true, s_red, s_scal);
  {
    float fb = oneplusf(s_ctrl[919+NR+q]);
    float d = powf(s_qb[q*NC+n]/s_scal[q], fb);
    s_qb[q*NC+n] = d;
    red4(s_qb, false, s_red, s_scal);
    s_bwd[q*NC+n] = d/s_scal[q];
  }

  // new memory norms (w-range split by q)
  {
    const float4* mr = (const float4*)(mem + mbase + (size_t)n*WL + q*32);
    float a=0.0f;
#pragma unroll
    for(int w4=0;w4<8;w4++){
      float4 m4 = mr[w4];
      a += m4.x*m4.x + m4.y*m4.y + m4.z*m4.z + m4.w*m4.w;
    }
    s_p16[q*NC+n]=a;
  }
  __syncthreads();
  if (q==0) s_mn[n] = sqrtf(s_p16[n]+s_p16[NC+n]+s_p16[2*NC+n]+s_p16[3*NC+n]);

  // read addressing: head = q, all 4 heads concurrent
  if (tid < NR*WL){ int r = tid>>7, w = tid&127; s_rkey[r*WL+w] = s_ctrl[WCH + r*(WL+4) + w]; }
  __syncthreads();
  {
    const float* kk = s_rkey + q*WL;
    float kn2r = 0.0f;
    for(int w=0;w<WL;w++) kn2r += kk[w]*kk[w];
    float knr = sqrtf(kn2r);
    float rbeta = oneplusf(s_ctrl[WCH + q*(WL+4) + WL]);
    const float4* mr = (const float4*)(mem + mbase + (size_t)n*WL);
    float dtr=0.0f;
#pragma unroll 4
    for(int w4=0;w4<32;w4++){
      float4 m4 = mr[w4];
      dtr += m4.x*kk[4*w4] + m4.y*kk[4*w4+1] + m4.z*kk[4*w4+2] + m4.w*kk[4*w4+3];
    }
    float lg = dtr/(knr*s_mn[n]+EPSF)*rbeta;
    s_qa[q*NC+n] = lg;
    red4(s_qa, true, s_red, s_scal);
    float er_ = expf(lg - s_scal[q]);
    s_qa[q*NC+n] = er_;
    red4(s_qa, false, s_red, s_scal);
    float cr = er_/s_scal[q];
    int mo = WCH + q*(WL+4) + WL + 1;
    float m0=s_ctrl[mo], m1m=s_ctrl[mo+1], m2m=s_ctrl[mo+2];
    float mm = fmaxf(m0,fmaxf(m1m,m2m));
    float e0=expf(m0-mm), e1=expf(m1m-mm), e2=expf(m2m-mm);
    float es=e0+e1+e2;
    float rdv = (e0*s_bwd[q*NC+n] + e1*cr + e2*s_fwd[q*NC+n])/es;
    __syncthreads();
    s_prd[q*NC+n] = rdv;
    r_dist[((size_t)b*NR+q)*NC + n] = rdv;
  }
  __syncthreads();

  // r_data (head = q): rdata[r][w] = sum_n prd[r][n]*mem[n][w], n split in halves
  {
    int w = n & (WL-1), half = n >> 7;
    float acc=0.0f;
    const float* mcol = mem + mbase + (size_t)half*128*WL + w;
    for(int i=0;i<128;i++) acc += s_prd[q*NC + half*128 + i]*mcol[(size_t)i*WL];
    s_qa[q*NC+n]=acc;
  }
  __syncthreads();
  if (tid < NR*WL){
    int r = tid>>7, w = tid&127;
    rdata[((size_t)b*NR+r)*WL + w] = s_qa[r*NC+w] + s_qa[r*NC+w+128];
  }
}

extern "C" void kernel_launch(void* const* d_in, const int* in_sizes, int n_in,
                              void* d_out, int out_size, void* d_ws, size_t ws_size,
                              hipStream_t stream) {
  const float* in_data = (const float*)d_in[0];
  const float* Wx      = (const float*)d_in[1];
  const float* Wh      = (const float*)d_in[2];
  const float* b_lstm  = (const float*)d_in[3];
  const float* Wc      = (const float*)d_in[4];
  const float* bc      = (const float*)d_in[5];
  const float* Wo      = (const float*)d_in[6];
  const float* bo      = (const float*)d_in[7];
  const float* Wr      = (const float*)d_in[8];
  const float* br      = (const float*)d_in[9];
  float* out = (float*)d_out;
  float* ws  = (float*)d_ws;

  size_t off = 0;
  float* mem_    = ws + off; off += (size_t)NB*NC*WL;   // 524288
  float* link_   = ws + off; off += (size_t)NB*NC*NC;   // 1048576
  float* usages_ = ws + off; off += NB*NC;
  float* prec_   = ws + off; off += NB*NC;
  float* wdist_  = ws + off; off += NB*NC;
  float* rdist_  = ws + off; off += NB*NR*NC;
  float* rdata_  = ws + off; off += NB*NR*WL;
  float* h0_     = ws + off; off += NB*HIDN;
  float* h1_     = ws + off; off += NB*HIDN;
  float* c0_     = ws + off; off += NB*HIDN;
  float* c1_     = ws + off; off += NB*HIDN;
  int*   bar_    = (int*)(ws + off); off += 16;
  size_t state_floats = off;
  float* gpart_  = ws + off; off += (size_t)16*NB*G4;   // 524288
  float* opart_  = ws + off; off += (size_t)4*NB*OUTS;  // 16384
  float* ctrl_   = ws + off; off += 14848;
  float* xpart_  = ws + off; off += (size_t)NT*NB*G4;   // 2097152

  k_zero<<<256,256,0,stream>>>(ws, (int)state_floats);
  k_xpart<<<1024,256,0,stream>>>(in_data, Wx, xpart_);

  for(int t=0;t<NT;t++){
    float* h_in  = (t&1) ? h1_ : h0_;
    float* h_out = (t&1) ? h0_ : h1_;
    float* c_in  = (t&1) ? c1_ : c0_;
    float* c_out = (t&1) ? c0_ : c1_;
    k_gates<<<320,256,0,stream>>>(Wx,Wh,Wo,Wr,h_in,rdata_,gpart_,opart_,t);
    k_fused<<<NBLK,FT,0,stream>>>(xpart_,gpart_,b_lstm,opart_,bo,br,Wc,bc,
                                  c_in,c_out,h_out,ctrl_,out,
                                  mem_,usages_,link_,prec_,wdist_,rdist_,rdata_,bar_,t);
  }
  // tail: out-head for t=63 (h(63) is in h0_)
  k_gates<<<320,256,0,stream>>>(Wx,Wh,Wo,Wr,h0_,rdata_,gpart_,opart_,NT);
  k_ored<<<16,256,0,stream>>>(opart_,bo,br,out);
}

// Round 3
// 8318.880 us; speedup vs baseline: 1.3687x; 1.0273x over previous
//
#include <hip/hip_runtime.h>
#include <math.h>

#define NT   64
#define NB   16
#define INS  256
#define OUTS 256
#define WL   128
#define NC   256
#define NR   4
#define HIDN 512
#define G4   2048
#define WCH  391
#define COUT 927
#define EPSF 1e-6f
#define NBLK 256
#define THR  512

__device__ __forceinline__ float sigf(float x){ return 1.0f/(1.0f+expf(-x)); }
__device__ __forceinline__ float oneplusf(float x){ return fmaxf(x,0.0f)+log1pf(expf(-fabsf(x)))+1.0f; }

__device__ __forceinline__ float waveSum(float v){
#pragma unroll
  for(int o=32;o>0;o>>=1) v += __shfl_down(v,o,64);
  return v;
}
__device__ __forceinline__ float waveMax(float v){
#pragma unroll
  for(int o=32;o>0;o>>=1) v = fmaxf(v,__shfl_down(v,o,64));
  return v;
}

__device__ __forceinline__ void g_storef(float* p, float v){
  __hip_atomic_store(p, v, __ATOMIC_RELAXED, __HIP_MEMORY_SCOPE_AGENT);
}
__device__ __forceinline__ float g_loadf(const float* p){
  return __hip_atomic_load((float*)p, __ATOMIC_RELAXED, __HIP_MEMORY_SCOPE_AGENT);
}

// fence-free grid barrier: counter + flag (no L2 writeback). All NBLK co-resident.
__device__ __forceinline__ void gridbar(int* bar, int* flag, int phase){
  __syncthreads();
  if (threadIdx.x == 0){
    asm volatile("s_waitcnt vmcnt(0) lgkmcnt(0)" ::: "memory");
    int prev = __hip_atomic_fetch_add(bar, 1, __ATOMIC_RELAXED, __HIP_MEMORY_SCOPE_AGENT);
    if (prev == NBLK*phase - 1){
      __hip_atomic_store(flag, phase, __ATOMIC_RELAXED, __HIP_MEMORY_SCOPE_AGENT);
    } else {
      while (__hip_atomic_load(flag, __ATOMIC_RELAXED, __HIP_MEMORY_SCOPE_AGENT) < phase)
        __builtin_amdgcn_s_sleep(4);
    }
    asm volatile("" ::: "memory");
  }
  __syncthreads();
}

// reduce a 256-row duplicated across both q-halves (512 threads). isMax or sum(/2).
__device__ float dup_reduce(float v, bool isMax, float* s_red){
  int lane=threadIdx.x&63, wid=threadIdx.x>>6;
  v = isMax ? waveMax(v) : waveSum(v);
  if(lane==0) s_red[wid]=v;
  __syncthreads();
  float r;
  if(isMax){ r=s_red[0]; for(int i=1;i<8;i++) r=fmaxf(r,s_red[i]); }
  else     { r=0.f; for(int i=0;i<8;i++) r+=s_red[i]; r*=0.5f; }
  __syncthreads();
  return r;
}

// reduce 8 rows of 256 in s_px -> s_scal[0..7]
__device__ void red8(const float* s_px, bool isMax, float* s_scal){
  int lane=threadIdx.x&63, w=threadIdx.x>>6;
  const float* r=s_px + w*256;
  float a=r[lane], b=r[lane+64], c=r[lane+128], d=r[lane+192];
  float v = isMax ? fmaxf(fmaxf(a,b),fmaxf(c,d)) : (a+b+c+d);
  v = isMax ? waveMax(v) : waveSum(v);
  if(lane==0) s_scal[w]=v;
  __syncthreads();
}
// reduce rows 0..3 (waves 4..7 duplicate) -> s_scal[0..3]
__device__ void red4d(const float* s_px, bool isMax, float* s_scal){
  int lane=threadIdx.x&63, w=threadIdx.x>>6; int row=w&3;
  const float* r=s_px + row*256;
  float a=r[lane], b=r[lane+64], c=r[lane+128], d=r[lane+192];
  float v = isMax ? fmaxf(fmaxf(a,b),fmaxf(c,d)) : (a+b+c+d);
  v = isMax ? waveMax(v) : waveSum(v);
  if(lane==0 && w<4) s_scal[row]=v;
  __syncthreads();
}

__global__ void k_zero(float* p, int n){
  int i = blockIdx.x*blockDim.x + threadIdx.x;
  int s = gridDim.x*blockDim.x;
  for(; i<n; i+=s) p[i]=0.0f;
}

// xpart[(t*NB+bi)*2048 + j] = x @ Wx[0:256] (once, fully parallel)
__global__ __launch_bounds__(256) void k_xpart(
    const float* __restrict__ in_data, const float* __restrict__ Wx, float* __restrict__ xpart)
{
  int jb = blockIdx.x & 15, rt = blockIdx.x >> 4;
  int jg = threadIdx.x & 15, rl = threadIdx.x >> 4;
  int row = rt*16 + rl;
  int j0 = jb*128 + jg*8;
  const float* x = in_data + (size_t)row*INS;
  float acc[8];
#pragma unroll
  for(int i=0;i<8;i++) acc[i]=0.0f;
  for(int k=0;k<INS;k++){
    float a = x[k];
    const float* w = Wx + (size_t)k*G4 + j0;
    float4 w0 = *(const float4*)w, w1 = *(const float4*)(w+4);
    acc[0]+=a*w0.x; acc[1]+=a*w0.y; acc[2]+=a*w0.z; acc[3]+=a*w0.w;
    acc[4]+=a*w1.x; acc[5]+=a*w1.y; acc[6]+=a*w1.z; acc[7]+=a*w1.w;
  }
  float* xp = xpart + (size_t)row*G4 + j0;
#pragma unroll
  for(int i=0;i<8;i++) xp[i]=acc[i];
}

// skewed act index: rows 0..511 rdata, 512..1023 h; [k][bi] with pad+skew
#define ACT(k,bi) ((k)*17 + (bi) + (((k)>>6)&31))

// LDS float offsets
#define O_WG    0        // 8196  : gates weights [k][8]+skew
#define O_WC    8196     // 2056  : ctrl weights [k][4]+skew
#define O_WO    10252    // 1056  : out weights [k]+skew
#define O_AC    11308    // 17472 : activations
#define O_CTRL  28780    // 928
#define O_PRD   29708    // 1024
#define O_FWD   30732    // 1024
#define O_BWD   31756    // 1024
#define O_U     32780    // 256
#define O_SU    33036    // 256
#define O_SHIFT 33292    // 256
#define O_WD    33548    // 256
#define O_PSI   33804    // 256
#define O_PRE   34060    // 256
#define O_MN    34316    // 256
#define O_ER    34572    // 128
#define O_PX    34700    // 2048
#define O_RED   36748    // 16
#define O_SCAL  36764    // 16
#define SH_FLOATS 36784

__global__ __launch_bounds__(THR,1) void k_persist(
    const float* __restrict__ Wx, const float* __restrict__ Wh, const float* __restrict__ b_lstm,
    const float* __restrict__ Wc, const float* __restrict__ bc,
    const float* __restrict__ Wo, const float* __restrict__ bo,
    const float* __restrict__ Wr, const float* __restrict__ br,
    const float* __restrict__ xpart,
    float* mem_g, float* link_g, float* usages_g, float* prec_g,
    float* wdist_g, float* rdist_g, float* rdata_g, float* h_g, float* c_g,
    float* ctrl_g, float* out_g, int* bar,
    float* __restrict__ Wall_dummy)
{
  extern __shared__ float SH[];
  const int tid = threadIdx.x, blk = blockIdx.x;
  float* s_wg   = SH + O_WG;
  float* s_wc   = SH + O_WC;
  float* s_wo   = SH + O_WO;
  float* s_act  = SH + O_AC;
  float* s_ctrl = SH + O_CTRL;
  float* s_prd  = SH + O_PRD;
  float* s_fwd  = SH + O_FWD;
  float* s_bwd  = SH + O_BWD;
  float* s_u    = SH + O_U;
  float* s_su   = SH + O_SU;
  float* s_shift= SH + O_SHIFT;
  float* s_wd   = SH + O_WD;
  float* s_psi  = SH + O_PSI;
  float* s_pre  = SH + O_PRE;
  float* s_mn   = SH + O_MN;
  float* s_er   = SH + O_ER;
  float* s_px   = SH + O_PX;
  float* s_red  = SH + O_RED;
  float* s_scal = SH + O_SCAL;
  int* flag = bar + 1;

  // ---- one-time: stage weights to LDS, zero act ----
  for(int i=tid;i<8192;i+=THR){
    int k=i>>3, c=i&7;
    int gcol = (c>>1)*512 + 2*blk + (c&1);
    s_wg[k*8+c+(k>>8)] = (k<512) ? Wx[(size_t)(256+k)*G4 + gcol]
                                 : Wh[(size_t)(k-512)*G4 + gcol];
  }
  if(blk<232){
    for(int i=tid;i<2048;i+=THR){
      int k=i>>2, jl=i&3; int j=4*blk+jl;
      s_wc[k*4+jl+(k>>6)] = (j<COUT) ? Wc[(size_t)k*COUT + j] : 0.f;
    }
  }
  for(int k=tid;k<1024;k+=THR){
    s_wo[k+(k>>5)] = (k<512) ? Wr[(size_t)k*OUTS + blk] : Wo[(size_t)(k-512)*OUTS + blk];
  }
  for(int i=tid;i<17472;i+=THR) s_act[i]=0.f;
  __syncthreads();

  int bcount=0;
  for(int t=0;t<=NT;t++){
    // ---- stage rdata(t-1) into act rows 0..511 ----
    for(int i=tid;i<8192;i+=THR){
      int bi=i>>9, k=i&511;
      s_act[ACT(k,bi)] = g_loadf(rdata_g + i);
    }
    __syncthreads();
    // ---- gates partials (t<NT) ----
    if(t<NT){
      int col=tid>>6, bi=(tid>>2)&15, kq=tid&3;
      float acc=0.f;
      for(int kk=0;kk<256;kk++){
        int k=kq*256+kk;
        acc += s_wg[k*8+col+(k>>8)] * s_act[ACT(k,bi)];
      }
      s_px[tid]=acc;
    }
    // ---- out(t-1) partials ----
    if(t>0){
      int bi=tid>>5, kq=tid&31;
      float acc=0.f;
      for(int kk=0;kk<32;kk++){
        int k=kq*32+kk;
        acc += s_wo[k+(k>>5)] * s_act[ACT(k,bi)];
      }
      s_px[1024+tid]=acc;
    }
    __syncthreads();
    if(t<NT && tid<128){
      int c=tid>>4, b2=tid&15; int p0=c*64+b2*4;
      s_px[1536+c*16+b2] = s_px[p0]+s_px[p0+1]+s_px[p0+2]+s_px[p0+3];
    }
    if(t>0 && tid>=128 && tid<144){
      int bi=tid-128;
      float acc=bo[blk]+br[blk];
      for(int kq=0;kq<32;kq++) acc += s_px[1024+bi*32+kq];
      out_g[(size_t)(t-1)*(NB*OUTS) + bi*OUTS + blk] = acc;
    }
    __syncthreads();
    if(t==NT) break;
    // ---- LSTM (2 jj per block x 16 bi = 32 threads) ----
    if(tid<32){
      int jl=tid&1, bi=tid>>1; int base=2*blk+jl;
      const float* xp = xpart + ((size_t)t*NB + bi)*G4;
      float g0 = s_px[1536+(0+jl)*16+bi] + xp[0*HIDN+base] + b_lstm[0*HIDN+base];
      float g1 = s_px[1536+(2+jl)*16+bi] + xp[1*HIDN+base] + b_lstm[1*HIDN+base];
      float g2 = s_px[1536+(4+jl)*16+bi] + xp[2*HIDN+base] + b_lstm[2*HIDN+base];
      float g3 = s_px[1536+(6+jl)*16+bi] + xp[3*HIDN+base] + b_lstm[3*HIDN+base];
      int ci = bi*HIDN+base;
      float c = sigf(g1)*c_g[ci] + sigf(g0)*tanhf(g2);
      float h = sigf(g3)*tanhf(c);
      c_g[ci]=c;
      g_storef(h_g+ci, h);
    }
    gridbar(bar,flag,++bcount);
    // ---- stage h(t) into act rows 512..1023; ctrl GEMM ----
    for(int i=tid;i<8192;i+=THR){
      int bi=i>>9, k=i&511;
      s_act[ACT(512+k,bi)] = g_loadf(h_g + i);
    }
    __syncthreads();
    if(blk<232){
      int jl=tid>>7, bi=(tid>>3)&15, kq=tid&7;
      float acc=0.f;
      for(int kk=0;kk<64;kk++){
        int k=kq*64+kk;
        acc += s_wc[k*4+jl+(k>>6)] * s_act[ACT(512+k,bi)];
      }
      s_px[tid]=acc;
      __syncthreads();
      if(tid<64){
        int jl2=tid>>4, bi2=tid&15; int j=4*blk+jl2;
        if(j<COUT){
          float a2=bc[j];
          for(int kq2=0;kq2<8;kq2++) a2 += s_px[jl2*128+bi2*8+kq2];
          g_storef(ctrl_g + bi2*COUT + j, fminf(fmaxf(a2,-20.f),20.f));
        }
      }
    }
    gridbar(bar,flag,++bcount);
    // ---- per-batch memory step (blocks 0..15) ----
    if(blk<16){
      const int b=blk, n=tid&255, q=tid>>8;
      for(int i=tid;i<COUT;i+=THR) s_ctrl[i]=g_loadf(ctrl_g + b*COUT + i);
      for(int i=tid;i<1024;i+=THR) s_prd[i]=rdist_g[b*1024+i];
      if(tid<256) s_pre[tid]=prec_g[b*NC+tid];
      __syncthreads();
      float w_beta=oneplusf(s_ctrl[388]);
      float a_gate=sigf(s_ctrl[389]);
      float w_gate=sigf(s_ctrl[390]);
      if(q==0){
        float psi=1.f;
#pragma unroll
        for(int r=0;r<NR;r++) psi *= 1.f - sigf(s_ctrl[384+r])*s_prd[r*NC+n];
        s_psi[n]=psi;
        float pw=wdist_g[b*NC+n];
        float u=usages_g[b*NC+n];
        u=(u+pw-u*pw)*psi;
        usages_g[b*NC+n]=u;
        s_u[n]=u*(1.f-EPSF)+EPSF;
      }
      if(tid<WL) s_er[tid]=sigf(s_ctrl[WL+tid]);
      __syncthreads();
      // stable rank
      {
        float u2=s_u[n]; int c=0;
        for(int jj=0;jj<128;jj++){
          int j=q*128+jj; float uj=s_u[j];
          c += (uj<u2) || (uj==u2 && j<n);
        }
        s_px[q*256+n]=(float)c;
      }
      __syncthreads();
      int rk=0;
      if(q==0){
        rk=(int)(s_px[n]+s_px[256+n]);
        s_su[rk]=s_u[n];
      }
      __syncthreads();
      if(tid==0){
        float run=1.f;
        for(int i=0;i<NC;i++){ s_shift[i]=run; run*=s_su[i]; }
      }
      __syncthreads();
      // write-key dot + old-mem norms (w split by q)
      size_t mb=(size_t)b*NC*WL;
      {
        const float4* mr=(const float4*)(mem_g + mb + (size_t)n*WL + q*64);
        float dt=0.f,m2=0.f;
#pragma unroll
        for(int w4=0;w4<16;w4++){
          float4 m=mr[w4]; int w=q*64+4*w4;
          dt += m.x*s_ctrl[w]+m.y*s_ctrl[w+1]+m.z*s_ctrl[w+2]+m.w*s_ctrl[w+3];
          m2 += m.x*m.x+m.y*m.y+m.z*m.z+m.w*m.w;
        }
        s_px[q*256+n]=dt; s_px[512+q*256+n]=m2;
      }
      float kn2=0.f;
      for(int w=0;w<WL;w++) kn2+=s_ctrl[w]*s_ctrl[w];
      __syncthreads();
      if(q==0){
        float dt=s_px[n]+s_px[256+n];
        float m2=s_px[512+n]+s_px[768+n];
        s_px[n]=dt*w_beta/(sqrtf(kn2)*sqrtf(m2)+EPSF);
      }
      __syncthreads();
      float v=s_px[n];
      float mx=dup_reduce(v,true,s_red);
      float e=expf(v-mx);
      float se=dup_reduce(e,false,s_red);
      if(q==0){
        float cw=e/se;
        float allocv=(1.f-s_su[rk])*s_shift[rk];
        float wd=w_gate*(a_gate*allocv+(1.f-a_gate)*cw);
        s_wd[n]=wd; wdist_g[b*NC+n]=wd;
      }
      __syncthreads();
      float swd=dup_reduce(s_wd[n],false,s_red);
      if(q==0) prec_g[b*NC+n]=(1.f-swd)*s_pre[n]+s_wd[n];
      // mem update, flat float4 coalesced
      {
        float4* m4p=(float4*)(mem_g+mb);
        const float4* er4=(const float4*)s_er;
        const float4* wv4=(const float4*)(s_ctrl+256);
#pragma unroll 4
        for(int i=0;i<16;i++){
          int g=i*THR+tid; int nn=g>>5, w4=g&31;
          float4 m=m4p[g];
          float ps=s_psi[nn], wdn=s_wd[nn];
          float4 er=er4[w4], wv=wv4[w4];
          m.x=m.x*ps*(1.f-wdn*er.x)+wdn*wv.x;
          m.y=m.y*ps*(1.f-wdn*er.y)+wdn*wv.y;
          m.z=m.z*ps*(1.f-wdn*er.z)+wdn*wv.z;
          m.w=m.w*ps*(1.f-wdn*er.w)+wdn*wv.w;
          m4p[g]=m;
        }
      }
      // link update (col n, i-half by q) + bwd partials
      {
        float wdn=s_wd[n], pren=s_pre[n];
        float bw0=0,bw1=0,bw2=0,bw3=0;
        float* lb=link_g + (size_t)b*NC*NC;
        for(int ii=0;ii<128;ii++){
          int i=q*128+ii;
          float l=lb[i*NC+n];
          float wi=s_wd[i];
          float ln=(i==n)?0.f:((1.f-wi-wdn)*l+wi*pren);
          lb[i*NC+n]=ln;
          bw0+=ln*s_prd[0*NC+i]; bw1+=ln*s_prd[1*NC+i];
          bw2+=ln*s_prd[2*NC+i]; bw3+=ln*s_prd[3*NC+i];
        }
        s_px[(q*4+0)*256+n]=bw0; s_px[(q*4+1)*256+n]=bw1;
        s_px[(q*4+2)*256+n]=bw2; s_px[(q*4+3)*256+n]=bw3;
      }
      __syncthreads();
#pragma unroll
      for(int rr=0;rr<2;rr++){
        int r=q*2+rr;
        s_bwd[r*NC+n]=s_px[r*256+n]+s_px[(4+r)*256+n];
      }
      __syncthreads();
      // fwd (row n, j-half by q)
      {
        float fw0=0,fw1=0,fw2=0,fw3=0;
        const float4* lr=(const float4*)(link_g + (size_t)b*NC*NC + (size_t)n*NC + q*128);
#pragma unroll 4
        for(int j4=0;j4<32;j4++){
          float4 l=lr[j4]; int j=q*128+4*j4;
          fw0+=l.x*s_prd[0*NC+j]+l.y*s_prd[0*NC+j+1]+l.z*s_prd[0*NC+j+2]+l.w*s_prd[0*NC+j+3];
          fw1+=l.x*s_prd[1*NC+j]+l.y*s_prd[1*NC+j+1]+l.z*s_prd[1*NC+j+2]+l.w*s_prd[1*NC+j+3];
          fw2+=l.x*s_prd[2*NC+j]+l.y*s_prd[2*NC+j+1]+l.z*s_prd[2*NC+j+2]+l.w*s_prd[2*NC+j+3];
          fw3+=l.x*s_prd[3*NC+j]+l.y*s_prd[3*NC+j+1]+l.z*s_prd[3*NC+j+2]+l.w*s_prd[3*NC+j+3];
        }
        s_px[(q*4+0)*256+n]=fw0; s_px[(q*4+1)*256+n]=fw1;
        s_px[(q*4+2)*256+n]=fw2; s_px[(q*4+3)*256+n]=fw3;
      }
      __syncthreads();
#pragma unroll
      for(int rr=0;rr<2;rr++){
        int r=q*2+rr;
        s_fwd[r*NC+n]=s_px[r*256+n]+s_px[(4+r)*256+n];
      }
      __syncthreads();
      // sharpen: rows 0..3 fwd, 4..7 bwd
#pragma unroll
      for(int rr=0;rr<4;rr++){
        int row=q*4+rr;
        float val=((row<4)? s_fwd[row*NC+n] : s_bwd[(row-4)*NC+n])+EPSF;
        s_px[row*256+n]=val;
      }
      __syncthreads();
      red8(s_px,true,s_scal);
#pragma unroll
      for(int rr=0;rr<4;rr++){
        int row=q*4+rr;
        float f=oneplusf(s_ctrl[919+row]);
        s_px[row*256+n]=powf(s_px[row*256+n]/s_scal[row],f);
      }
      __syncthreads();
      red8(s_px,false,s_scal);
#pragma unroll
      for(int rr=0;rr<4;rr++){
        int row=q*4+rr;
        float vv=s_px[row*256+n]/s_scal[row];
        if(row<4) s_fwd[row*NC+n]=vv; else s_bwd[(row-4)*NC+n]=vv;
      }
      __syncthreads();
      // read dots + new mem norms
      {
        const float4* mr=(const float4*)(mem_g + mb + (size_t)n*WL + q*64);
        float d0=0,d1=0,d2=0,d3=0,m2=0;
#pragma unroll
        for(int w4=0;w4<16;w4++){
          float4 m=mr[w4]; int w=q*64+4*w4;
          const float* k0=s_ctrl+WCH+0*132;
          const float* k1=s_ctrl+WCH+1*132;
          const float* k2=s_ctrl+WCH+2*132;
          const float* k3=s_ctrl+WCH+3*132;
          d0+=m.x*k0[w]+m.y*k0[w+1]+m.z*k0[w+2]+m.w*k0[w+3];
          d1+=m.x*k1[w]+m.y*k1[w+1]+m.z*k1[w+2]+m.w*k1[w+3];
          d2+=m.x*k2[w]+m.y*k2[w+1]+m.z*k2[w+2]+m.w*k2[w+3];
          d3+=m.x*k3[w]+m.y*k3[w+1]+m.z*k3[w+2]+m.w*k3[w+3];
          m2+=m.x*m.x+m.y*m.y+m.z*m.z+m.w*m.w;
        }
        s_px[(q*4+0)*256+n]=d0; s_px[(q*4+1)*256+n]=d1;
        s_px[(q*4+2)*256+n]=d2; s_px[(q*4+3)*256+n]=d3;
        if(q==0) s_shift[n]=m2; else s_su[n]=m2;
      }
      // per-head key norms (waves 0..3)
      {
        int lane=tid&63, wid=tid>>6;
        if(wid<4){
          const float* kk=s_ctrl+WCH+wid*132;
          float kv=kk[lane]*kk[lane]+kk[lane+64]*kk[lane+64];
          kv=waveSum(kv);
          if(lane==0) s_scal[8+wid]=kv;
        }
      }
      __syncthreads();
      if(q==0){
        s_mn[n]=sqrtf(s_shift[n]+s_su[n]);
      }
      __syncthreads();
      if(q==0){
#pragma unroll
        for(int r=0;r<NR;r++){
          float dt=s_px[r*256+n]+s_px[(4+r)*256+n];
          float rb=oneplusf(s_ctrl[WCH+r*132+128]);
          s_px[r*256+n]=dt*rb/(sqrtf(s_scal[8+r])*s_mn[n]+EPSF);
        }
      }
      __syncthreads();
      red4d(s_px,true,s_scal);
      if(q==0){
#pragma unroll
        for(int r=0;r<NR;r++) s_px[r*256+n]=expf(s_px[r*256+n]-s_scal[r]);
      }
      __syncthreads();
      red4d(s_px,false,s_scal);
      if(q==0){
#pragma unroll
        for(int r=0;r<NR;r++){
          float cr=s_px[r*256+n]/s_scal[r];
          int mo=WCH+r*132+129;
          float m0=s_ctrl[mo],m1=s_ctrl[mo+1],m2s=s_ctrl[mo+2];
          float mm=fmaxf(m0,fmaxf(m1,m2s));
          float e0=expf(m0-mm),e1=expf(m1-mm),e2=expf(m2s-mm);
          float es=e0+e1+e2;
          float rdv=(e0*s_bwd[r*NC+n]+e1*cr+e2*s_fwd[r*NC+n])/es;
          s_prd[r*NC+n]=rdv;
          rdist_g[b*1024+r*NC+n]=rdv;
        }
      }
      __syncthreads();
      // rdata: thread (chunk=tid>>7, w=tid&127), i over chunk*64..+64
      {
        int w=tid&127, ch=tid>>7;
        float a0=0,a1=0,a2=0,a3=0;
        const float* mp=mem_g+mb;
        for(int ii=0;ii<64;ii++){
          int i=ch*64+ii;
          float mv=mp[(size_t)i*WL+w];
          a0+=s_prd[0*NC+i]*mv; a1+=s_prd[1*NC+i]*mv;
          a2+=s_prd[2*NC+i]*mv; a3+=s_prd[3*NC+i]*mv;
        }
        s_px[(ch*4+0)*128+w]=a0; s_px[(ch*4+1)*128+w]=a1;
        s_px[(ch*4+2)*128+w]=a2; s_px[(ch*4+3)*128+w]=a3;
      }
      __syncthreads();
      {
        int r=tid>>7, w=tid&127;
        float rd=s_px[(0*4+r)*128+w]+s_px[(1*4+r)*128+w]+s_px[(2*4+r)*128+w]+s_px[(3*4+r)*128+w];
        g_storef(rdata_g + b*512 + r*WL + w, rd);
      }
    }
    gridbar(bar,flag,++bcount);
  }
}

extern "C" void kernel_launch(void* const* d_in, const int* in_sizes, int n_in,
                              void* d_out, int out_size, void* d_ws, size_t ws_size,
                              hipStream_t stream) {
  const float* in_data = (const float*)d_in[0];
  const float* Wx      = (const float*)d_in[1];
  const float* Wh      = (const float*)d_in[2];
  const float* b_lstm  = (const float*)d_in[3];
  const float* Wc      = (const float*)d_in[4];
  const float* bc      = (const float*)d_in[5];
  const float* Wo      = (const float*)d_in[6];
  const float* bo      = (const float*)d_in[7];
  const float* Wr      = (const float*)d_in[8];
  const float* br      = (const float*)d_in[9];
  float* out = (float*)d_out;
  float* ws  = (float*)d_ws;

  size_t off=0;
  float* mem_    = ws+off; off += (size_t)NB*NC*WL;    // 524288
  float* link_   = ws+off; off += (size_t)NB*NC*NC;    // 1048576
  float* usages_ = ws+off; off += NB*NC;               // 4096
  float* prec_   = ws+off; off += NB*NC;
  float* wdist_  = ws+off; off += NB*NC;
  float* rdist_  = ws+off; off += NB*NR*NC;            // 16384
  float* rdata_  = ws+off; off += NB*NR*WL;            // 8192
  float* h_      = ws+off; off += NB*HIDN;             // 8192
  float* c_      = ws+off; off += NB*HIDN;
  float* ctrl_   = ws+off; off += 14848;               // NB*COUT padded
  int*   bar_    = (int*)(ws+off); off += 16;
  size_t state_floats = off;
  float* xpart_  = ws+off; off += (size_t)NT*NB*G4;    // 2097152

  static const size_t SH_BYTES = SH_FLOATS*sizeof(float);
  hipFuncSetAttribute((const void*)k_persist,
                      hipFuncAttributeMaxDynamicSharedMemorySize, (int)SH_BYTES);

  k_zero<<<256,256,0,stream>>>(ws, (int)state_floats);
  k_xpart<<<1024,256,0,stream>>>(in_data, Wx, xpart_);
  k_persist<<<NBLK,THR,SH_BYTES,stream>>>(Wx,Wh,b_lstm,Wc,bc,Wo,bo,Wr,br,
                                          xpart_,mem_,link_,usages_,prec_,
                                          wdist_,rdist_,rdata_,h_,c_,
                                          ctrl_,out,bar_,nullptr);
}